// Round 14
// baseline (377.740 us; speedup 1.0000x reference)
//
#include <hip/hip_runtime.h>
#include <hip/hip_bf16.h>
#include <math.h>

// Problem constants (B=1, S=2048, H=1024, E=8, F=3584, K=2)
namespace {
constexpr int kT = 2048;   // tokens
constexpr int kH = 1024;   // hidden
constexpr int kE = 8;      // experts
constexpr int kF = 3584;   // ffn dim
constexpr int kK = 2;      // top-k

// workspace layout (bytes)
constexpr size_t OFF_CNT  = 0;                                // int[8]
constexpr size_t OFF_LIST = 1024;                             // int[8][2048]
constexpr size_t OFF_RW   = OFF_LIST + sizeof(int) * kE * kT; // float[4096]
constexpr size_t OFF_HMID = 1u << 20;                         // bf16[4096][3584] = 28.7 MB
// fast path: contiguous bf16 mirror  xb | w1b | w3b | w2b
constexpr size_t OFF_XB   = 32u << 20;
constexpr size_t SZ_XB    = (size_t)kT * kH * 2;              // 4 MB
constexpr size_t SZ_W     = (size_t)kE * kF * kH * 2;         // 56 MB
constexpr size_t OFF_W1B  = OFF_XB + SZ_XB;
constexpr size_t OFF_W3B  = OFF_W1B + SZ_W;
constexpr size_t OFF_W2B  = OFF_W3B + SZ_W;
constexpr size_t WS_NEED  = OFF_W2B + SZ_W;                   // ~204 MB

constexpr long NX8  = (long)kT * kH / 8;          // 262,144
constexpr long NW8  = (long)kE * kF * kH / 8;     // 3,670,016
constexpr long TOT8 = NX8 + 3 * NW8;

typedef __attribute__((ext_vector_type(8))) short bf16x8;     // 8 bf16 in 4 VGPRs
typedef __attribute__((ext_vector_type(4))) float fx4;
}

// f32 -> bf16 via compiler intrinsic (emits v_cvt_pk_bf16_f32 pairs)
__device__ __forceinline__ short f2bf_s(float f) {
  union { __hip_bfloat16 h; short s; } u;
  u.h = __float2bfloat16(f);
  return u.s;
}

__device__ __forceinline__ bf16x8 pack8(float4 a, float4 b) {
  bf16x8 r;
  r[0] = f2bf_s(a.x); r[1] = f2bf_s(a.y);
  r[2] = f2bf_s(a.z); r[3] = f2bf_s(a.w);
  r[4] = f2bf_s(b.x); r[5] = f2bf_s(b.y);
  r[6] = f2bf_s(b.z); r[7] = f2bf_s(b.w);
  return r;
}

__device__ __forceinline__ bf16x8 pack8v(fx4 a, fx4 b) {
  bf16x8 r;
  r[0] = f2bf_s(a[0]); r[1] = f2bf_s(a[1]);
  r[2] = f2bf_s(a[2]); r[3] = f2bf_s(a[3]);
  r[4] = f2bf_s(b[0]); r[5] = f2bf_s(b[1]);
  r[6] = f2bf_s(b[2]); r[7] = f2bf_s(b[3]);
  return r;
}

// LDS rows of 64 bf16 (128 B) = 8 x 16B units; XOR unit by (row&7).
// 0 bank conflicts measured (R4-R13). global_load_lds path: LDS dst LINEAR,
// XOR on the per-lane GLOBAL source address (rule #21 pairing), swz() on read.
__device__ __forceinline__ int swz(int row, int u) {
  return row * 64 + ((u ^ (row & 7)) << 3);   // index in shorts
}

// async 16B global->LDS (gfx950); dst = wave-uniform base + lane*16.
__device__ __forceinline__ void gload16(const void* g, void* l) {
  __builtin_amdgcn_global_load_lds(
      (const __attribute__((address_space(1))) void*)g,
      (__attribute__((address_space(3))) void*)l, 16, 0, 0);
}

// ---------------------------------------------------------------------------
// Fused f32 -> bf16 cast (one launch). ~103 us measured = HBM roofline for
// its 676 MB of traffic (107 us at 6.3 TB/s). Do not touch.
// ---------------------------------------------------------------------------
__global__ __launch_bounds__(256) void cast_all_kernel(
    const float* __restrict__ x, const float* __restrict__ w1,
    const float* __restrict__ w3, const float* __restrict__ w2,
    unsigned short* __restrict__ dst) {
  long i = (long)blockIdx.x * blockDim.x + threadIdx.x;
  const long stride = (long)gridDim.x * blockDim.x;
  for (; i < TOT8; i += stride) {
    const float* s; long o;
    if (i < NX8)              { s = x;  o = i; }
    else if (i < NX8 + NW8)   { s = w1; o = i - NX8; }
    else if (i < NX8 + 2*NW8) { s = w3; o = i - NX8 - NW8; }
    else                      { s = w2; o = i - NX8 - 2*NW8; }
    const fx4* sp = reinterpret_cast<const fx4*>(s + o * 8);
    const fx4 v0 = __builtin_nontemporal_load(sp);
    const fx4 v1 = __builtin_nontemporal_load(sp + 1);
    *reinterpret_cast<bf16x8*>(dst + i * 8) = pack8v(v0, v1);
  }
}

// ---------------------------------------------------------------------------
// Router (f32, exact — expert selection must not move).
// ---------------------------------------------------------------------------
__global__ __launch_bounds__(256) void router_kernel(
    const float* __restrict__ x, const float* __restrict__ gw,
    float* __restrict__ logits_out, int* __restrict__ cnt,
    int* __restrict__ list, float* __restrict__ rw) {
  const int t = blockIdx.x;
  const float* xt = x + (size_t)t * kH;
  __shared__ float lg[kE];
  const int wave = threadIdx.x >> 6;
  const int lane = threadIdx.x & 63;
  for (int e = wave; e < kE; e += 4) {
    const float* g = gw + (size_t)e * kH;
    float s = 0.f;
    for (int h = lane; h < kH; h += 64) s += xt[h] * g[h];
#pragma unroll
    for (int off = 32; off > 0; off >>= 1) s += __shfl_down(s, off, 64);
    if (lane == 0) lg[e] = s;
  }
  __syncthreads();
  if (threadIdx.x < kE) logits_out[(size_t)t * kE + threadIdx.x] = lg[threadIdx.x];
  if (threadIdx.x == 0) {
    float m = lg[0];
#pragma unroll
    for (int e = 1; e < kE; ++e) m = fmaxf(m, lg[e]);
    float p[kE];
#pragma unroll
    for (int e = 0; e < kE; ++e) p[e] = expf(lg[e] - m);
    int i0 = 0;
#pragma unroll
    for (int e = 1; e < kE; ++e) if (p[e] > p[i0]) i0 = e;
    int i1 = (i0 == 0) ? 1 : 0;
#pragma unroll
    for (int e = 0; e < kE; ++e)
      if (e != i0 && e != i1 && p[e] > p[i1]) i1 = e;
    const float w0 = p[i0], w1v = p[i1];
    const float inv = 1.f / (w0 + w1v);
    rw[t * kK + 0] = w0 * inv;
    rw[t * kK + 1] = w1v * inv;
    const int s0 = atomicAdd(&cnt[i0], 1);
    list[i0 * kT + s0] = t * kK + 0;
    const int s1 = atomicAdd(&cnt[i1], 1);
    list[i1 * kT + s1] = t * kK + 1;
  }
}

// ===========================================================================
// FAST PATH: counted-vmcnt pipeline (T4).
// ===========================================================================

// GEMM1 (RE-TILED this round): BM 128->256. Theory: staging was L2-BW-bound
// (B panels re-read by 16 M-tiles = ~2 GB L2 traffic ~ 20 TB/s). BM=256
// halves B re-reads. 4 waves stacked in M (wave tile 64x64), 64 MFMA/iter,
// 12 gload16/thread/stage, LDS 98KB (1 block/CU — vmcnt pipeline still
// keeps loads in flight across barriers).
__global__ __launch_bounds__(256) void moe_mid_gl(
    const unsigned short* __restrict__ xb, const unsigned short* __restrict__ w1b,
    const unsigned short* __restrict__ w3b, const int* __restrict__ cnt,
    const int* __restrict__ list, unsigned short* __restrict__ hmid) {
  const int e = blockIdx.z;
  const int n = cnt[e];
  const int t0 = blockIdx.y * 256;
  if (t0 >= n) return;
  const int f0 = blockIdx.x * 64;

  __shared__ short As[2][256 * 64];    // 32 KB per buf
  __shared__ short B1s[2][64 * 64];    // 8 KB per buf
  __shared__ short B3s[2][64 * 64];
  __shared__ int ppid[256];
  __shared__ int ptok[256];

  const int tid = threadIdx.x;
  {
    const int idx = t0 + tid;
    const int pid = (idx < n) ? list[e * kT + idx] : -1;
    ppid[tid] = pid;
    ptok[tid] = (pid < 0) ? 0 : (pid >> 1);
  }
  __syncthreads();   // drains list loads -> vmcnt 0 baseline

  const unsigned short* w1e = w1b + (size_t)e * kF * kH;
  const unsigned short* w3e = w3b + (size_t)e * kF * kH;

  // staging maps (pre-swizzled global sources, linear LDS dst)
  const unsigned short* a_src[8];
#pragma unroll
  for (int c = 0; c < 8; ++c) {
    const int flat = tid + 256 * c;
    const int row = flat >> 3, u = flat & 7;
    a_src[c] = xb + (size_t)ptok[row] * kH + ((u ^ (row & 7)) * 8);
  }
  const unsigned short* b1_src[2]; const unsigned short* b3_src[2];
#pragma unroll
  for (int c = 0; c < 2; ++c) {
    const int flat = tid + 256 * c;
    const int row = flat >> 3, u = flat & 7;
    const int co = (u ^ (row & 7)) * 8;
    b1_src[c] = w1e + (size_t)(f0 + row) * kH + co;
    b3_src[c] = w3e + (size_t)(f0 + row) * kH + co;
  }

  const int lane = tid & 63, wid = tid >> 6;
  const int lr = lane & 15, lq = lane >> 4;

  fx4 acc1[4][4], acc3[4][4];
#pragma unroll
  for (int i = 0; i < 4; ++i)
#pragma unroll
    for (int j = 0; j < 4; ++j) { acc1[i][j] = (fx4)(0.f); acc3[i][j] = (fx4)(0.f); }

  auto STAGE = [&](int buf, int k0) {
#pragma unroll
    for (int c = 0; c < 8; ++c)
      gload16(a_src[c] + k0, &As[buf][(tid + 256 * c) * 8]);
#pragma unroll
    for (int c = 0; c < 2; ++c) {
      gload16(b1_src[c] + k0, &B1s[buf][(tid + 256 * c) * 8]);
      gload16(b3_src[c] + k0, &B3s[buf][(tid + 256 * c) * 8]);
    }
  };
  auto MFMA_PHASE = [&](int buf) {
    const short* Ab = As[buf]; const short* B1b = B1s[buf]; const short* B3b = B3s[buf];
    __builtin_amdgcn_s_setprio(1);
#pragma unroll
    for (int ks = 0; ks < 2; ++ks) {
      bf16x8 a[4], bb1[4], bb3[4];
#pragma unroll
      for (int mi = 0; mi < 4; ++mi)
        a[mi] = *reinterpret_cast<const bf16x8*>(&Ab[swz(wid * 64 + mi * 16 + lr, ks * 4 + lq)]);
#pragma unroll
      for (int ni = 0; ni < 4; ++ni) {
        bb1[ni] = *reinterpret_cast<const bf16x8*>(&B1b[swz(ni * 16 + lr, ks * 4 + lq)]);
        bb3[ni] = *reinterpret_cast<const bf16x8*>(&B3b[swz(ni * 16 + lr, ks * 4 + lq)]);
      }
#pragma unroll
      for (int mi = 0; mi < 4; ++mi)
#pragma unroll
        for (int ni = 0; ni < 4; ++ni) {
          acc1[mi][ni] = __builtin_amdgcn_mfma_f32_16x16x32_bf16(a[mi], bb1[ni], acc1[mi][ni], 0, 0, 0);
          acc3[mi][ni] = __builtin_amdgcn_mfma_f32_16x16x32_bf16(a[mi], bb3[ni], acc3[mi][ni], 0, 0, 0);
        }
    }
    __builtin_amdgcn_s_setprio(0);
  };

  constexpr int NIT = kH / 64;  // 16
  STAGE(0, 0);
  STAGE(1, 64);                 // 24 loads in flight per thread
  for (int it = 0; it < NIT; ++it) {
    const int cur = it & 1;
    if (it + 1 < NIT) asm volatile("s_waitcnt vmcnt(12)" ::: "memory");
    else              asm volatile("s_waitcnt vmcnt(0)" ::: "memory");
    asm volatile("s_barrier" ::: "memory");
    MFMA_PHASE(cur);
    asm volatile("s_barrier" ::: "memory");
    if (it + 2 < NIT) STAGE(cur, (it + 2) * 64);
  }

#pragma unroll
  for (int mi = 0; mi < 4; ++mi)
#pragma unroll
    for (int i = 0; i < 4; ++i) {
      const int row = wid * 64 + mi * 16 + lq * 4 + i;
      const int pid = ppid[row];
      if (pid < 0) continue;
#pragma unroll
      for (int ni = 0; ni < 4; ++ni) {
        const int col = f0 + ni * 16 + lr;
        const float s1 = acc1[mi][ni][i];
        const float s3 = acc3[mi][ni][i];
        const float h = s1 * s3 / (1.f + expf(-s1));  // silu(s1)*s3
        hmid[(size_t)pid * kF + col] = (unsigned short)f2bf_s(h);
      }
    }
}

// GEMM2 (unchanged from R13 — control): 128p x 128h, BK=64, 32 MFMA/iter.
__global__ __launch_bounds__(256) void moe_out_gl(
    const unsigned short* __restrict__ hmid, const unsigned short* __restrict__ w2b,
    const int* __restrict__ cnt, const int* __restrict__ list,
    const float* __restrict__ rw, float* __restrict__ out) {
  const int e = blockIdx.z;
  const int n = cnt[e];
  const int p0 = blockIdx.y * 128;
  if (p0 >= n) return;
  const int h0 = blockIdx.x * 128;

  __shared__ short As[2][128 * 64];
  __shared__ short Bs[2][128 * 64];
  __shared__ int ppid[128];
  __shared__ int prow[128];

  const int tid = threadIdx.x;
  if (tid < 128) {
    const int idx = p0 + tid;
    const int pid = (idx < n) ? list[e * kT + idx] : -1;
    ppid[tid] = pid;
    prow[tid] = (pid < 0) ? 0 : pid;
  }
  __syncthreads();

  const unsigned short* w2e = w2b + (size_t)e * kH * kF;

  const unsigned short* a_src[4];
#pragma unroll
  for (int c = 0; c < 4; ++c) {
    const int flat = tid + 256 * c;
    const int row = flat >> 3, u = flat & 7;
    a_src[c] = hmid + (size_t)prow[row] * kF + ((u ^ (row & 7)) * 8);
  }
  const unsigned short* b_src[4];
#pragma unroll
  for (int c = 0; c < 4; ++c) {
    const int flat = tid + 256 * c;
    const int row = flat >> 3, u = flat & 7;
    b_src[c] = w2e + (size_t)(h0 + row) * kF + ((u ^ (row & 7)) * 8);
  }

  const int lane = tid & 63, wid = tid >> 6;
  const int wr = wid >> 1, wc = wid & 1;
  const int lr = lane & 15, lq = lane >> 4;

  fx4 acc[4][4];
#pragma unroll
  for (int i = 0; i < 4; ++i)
#pragma unroll
    for (int j = 0; j < 4; ++j) acc[i][j] = (fx4)(0.f);

  auto STAGE = [&](int buf, int k0) {
#pragma unroll
    for (int c = 0; c < 4; ++c)
      gload16(a_src[c] + k0, &As[buf][(tid + 256 * c) * 8]);
#pragma unroll
    for (int c = 0; c < 4; ++c)
      gload16(b_src[c] + k0, &Bs[buf][(tid + 256 * c) * 8]);
  };
  auto MFMA_PHASE = [&](int buf) {
    const short* Ab = As[buf]; const short* Bb = Bs[buf];
    __builtin_amdgcn_s_setprio(1);
#pragma unroll
    for (int ks = 0; ks < 2; ++ks) {
      bf16x8 a[4], b[4];
#pragma unroll
      for (int mi = 0; mi < 4; ++mi)
        a[mi] = *reinterpret_cast<const bf16x8*>(&Ab[swz(wr * 64 + mi * 16 + lr, ks * 4 + lq)]);
#pragma unroll
      for (int ni = 0; ni < 4; ++ni)
        b[ni] = *reinterpret_cast<const bf16x8*>(&Bb[swz(wc * 64 + ni * 16 + lr, ks * 4 + lq)]);
#pragma unroll
      for (int mi = 0; mi < 4; ++mi)
#pragma unroll
        for (int ni = 0; ni < 4; ++ni)
          acc[mi][ni] = __builtin_amdgcn_mfma_f32_16x16x32_bf16(a[mi], b[ni], acc[mi][ni], 0, 0, 0);
    }
    __builtin_amdgcn_s_setprio(0);
  };

  constexpr int NIT = kF / 64;  // 56
  STAGE(0, 0);
  STAGE(1, 64);
  for (int it = 0; it < NIT; ++it) {
    const int cur = it & 1;
    if (it + 1 < NIT) asm volatile("s_waitcnt vmcnt(8)" ::: "memory");
    else              asm volatile("s_waitcnt vmcnt(0)" ::: "memory");
    asm volatile("s_barrier" ::: "memory");
    MFMA_PHASE(cur);
    asm volatile("s_barrier" ::: "memory");
    if (it + 2 < NIT) STAGE(cur, (it + 2) * 64);
  }

#pragma unroll
  for (int mi = 0; mi < 4; ++mi)
#pragma unroll
    for (int i = 0; i < 4; ++i) {
      const int row = wr * 64 + mi * 16 + lq * 4 + i;
      const int pid = ppid[row];
      if (pid < 0) continue;
      const int tok = pid >> 1;
      const float w = rw[pid];
      float* op = out + (size_t)tok * kH + h0 + wc * 64 + lr;
#pragma unroll
      for (int ni = 0; ni < 4; ++ni)
        atomicAdd(&op[ni * 16], w * acc[mi][ni][i]);
    }
}

// ===========================================================================
// FALLBACK PATH (ws too small): R7 kernels, known-good 342 us.
// ===========================================================================
struct StageM { float4 a[2][2], b1[2][2], b3[2][2]; };

__global__ __launch_bounds__(256) void moe_mid_mfma(
    const float* __restrict__ x, const float* __restrict__ w1,
    const float* __restrict__ w3, const int* __restrict__ cnt,
    const int* __restrict__ list, unsigned short* __restrict__ hmid) {
  const int e = blockIdx.z;
  const int n = cnt[e];
  const int t0 = blockIdx.y * 64;
  if (t0 >= n) return;
  const int f0 = blockIdx.x * 64;

  __shared__ short As[2][64 * 64];
  __shared__ short B1s[2][64 * 64];
  __shared__ short B3s[2][64 * 64];
  __shared__ int ppid[64];
  __shared__ int ptok[64];

  const int tid = threadIdx.x;
  if (tid < 64) {
    const int idx = t0 + tid;
    const int pid = (idx < n) ? list[e * kT + idx] : -1;
    ppid[tid] = pid;
    ptok[tid] = (pid < 0) ? 0 : (pid >> 1);
  }
  __syncthreads();

  const float* w1e = w1 + (size_t)e * kF * kH;
  const float* w3e = w3 + (size_t)e * kF * kH;

  const float* a_src[2]; const float* b1_src[2]; const float* b3_src[2];
  int sw_[2];
#pragma unroll
  for (int i = 0; i < 2; ++i) {
    const int flat = tid + 256 * i;
    const int row = flat >> 3, u = flat & 7;
    a_src[i]  = x + (size_t)ptok[row] * kH + u * 8;
    b1_src[i] = w1e + (size_t)(f0 + row) * kH + u * 8;
    b3_src[i] = w3e + (size_t)(f0 + row) * kH + u * 8;
    sw_[i] = swz(row, u);
  }

  const int lane = tid & 63, wid = tid >> 6;
  const int wr = wid >> 1, wc = wid & 1;
  const int lr = lane & 15, lq = lane >> 4;

  fx4 acc1[2][2], acc3[2][2];
#pragma unroll
  for (int i = 0; i < 2; ++i)
#pragma unroll
    for (int j = 0; j < 2; ++j) { acc1[i][j] = (fx4)(0.f); acc3[i][j] = (fx4)(0.f); }

  auto LOAD = [&](StageM& S, int k0) {
#pragma unroll
    for (int i = 0; i < 2; ++i) {
      S.a[i][0]  = *reinterpret_cast<const float4*>(a_src[i] + k0);
      S.a[i][1]  = *reinterpret_cast<const float4*>(a_src[i] + k0 + 4);
      S.b1[i][0] = *reinterpret_cast<const float4*>(b1_src[i] + k0);
      S.b1[i][1] = *reinterpret_cast<const float4*>(b1_src[i] + k0 + 4);
      S.b3[i][0] = *reinterpret_cast<const float4*>(b3_src[i] + k0);
      S.b3[i][1] = *reinterpret_cast<const float4*>(b3_src[i] + k0 + 4);
    }
  };
  auto STORE = [&](const StageM& S, int buf) {
#pragma unroll
    for (int i = 0; i < 2; ++i) {
      *reinterpret_cast<bf16x8*>(&As[buf][sw_[i]])  = pack8(S.a[i][0], S.a[i][1]);
      *reinterpret_cast<bf16x8*>(&B1s[buf][sw_[i]]) = pack8(S.b1[i][0], S.b1[i][1]);
      *reinterpret_cast<bf16x8*>(&B3s[buf][sw_[i]]) = pack8(S.b3[i][0], S.b3[i][1]);
    }
  };
  auto MFMA_PHASE = [&](int buf) {
    const short* Ab = As[buf]; const short* B1b = B1s[buf]; const short* B3b = B3s[buf];
    __builtin_amdgcn_s_setprio(1);
#pragma unroll
    for (int ks = 0; ks < 2; ++ks) {
      bf16x8 a[2], bb1[2], bb3[2];
#pragma unroll
      for (int mi = 0; mi < 2; ++mi)
        a[mi] = *reinterpret_cast<const bf16x8*>(&Ab[swz(wr * 32 + mi * 16 + lr, ks * 4 + lq)]);
#pragma unroll
      for (int ni = 0; ni < 2; ++ni) {
        bb1[ni] = *reinterpret_cast<const bf16x8*>(&B1b[swz(wc * 32 + ni * 16 + lr, ks * 4 + lq)]);
        bb3[ni] = *reinterpret_cast<const bf16x8*>(&B3b[swz(wc * 32 + ni * 16 + lr, ks * 4 + lq)]);
      }
#pragma unroll
      for (int mi = 0; mi < 2; ++mi)
#pragma unroll
        for (int ni = 0; ni < 2; ++ni) {
          acc1[mi][ni] = __builtin_amdgcn_mfma_f32_16x16x32_bf16(a[mi], bb1[ni], acc1[mi][ni], 0, 0, 0);
          acc3[mi][ni] = __builtin_amdgcn_mfma_f32_16x16x32_bf16(a[mi], bb3[ni], acc3[mi][ni], 0, 0, 0);
        }
    }
    __builtin_amdgcn_s_setprio(0);
  };

  StageM R0, R1;
  constexpr int NIT = kH / 64;
  LOAD(R0, 0);
  LOAD(R1, 64);
  STORE(R0, 0);
  __syncthreads();
#pragma unroll 2
  for (int it = 0; it < NIT; ++it) {
    if (it & 1) {
      if (it + 2 < NIT) LOAD(R1, (it + 2) * 64);
      MFMA_PHASE(1);
      if (it + 1 < NIT) STORE(R0, 0);
    } else {
      if (it + 2 < NIT) LOAD(R0, (it + 2) * 64);
      MFMA_PHASE(0);
      if (it + 1 < NIT) STORE(R1, 1);
    }
    __syncthreads();
  }

#pragma unroll
  for (int mi = 0; mi < 2; ++mi)
#pragma unroll
    for (int i = 0; i < 4; ++i) {
      const int row = wr * 32 + mi * 16 + lq * 4 + i;
      const int pid = ppid[row];
      if (pid < 0) continue;
#pragma unroll
      for (int ni = 0; ni < 2; ++ni) {
        const int col = f0 + wc * 32 + ni * 16 + lr;
        const float s1 = acc1[mi][ni][i];
        const float s3 = acc3[mi][ni][i];
        const float h = s1 * s3 / (1.f + expf(-s1));
        hmid[(size_t)pid * kF + col] = (unsigned short)f2bf_s(h);
      }
    }
}

struct StageO { bf16x8 a[2]; float4 b[2][2]; };

__global__ __launch_bounds__(256) void moe_out_mfma(
    const unsigned short* __restrict__ hmid, const float* __restrict__ w2,
    const int* __restrict__ cnt, const int* __restrict__ list,
    const float* __restrict__ rw, float* __restrict__ out) {
  const int e = blockIdx.z;
  const int n = cnt[e];
  const int p0 = blockIdx.y * 64;
  if (p0 >= n) return;
  const int h0 = blockIdx.x * 64;

  __shared__ short As[2][64 * 64];
  __shared__ short Bs[2][64 * 64];
  __shared__ int ppid[64];
  __shared__ int prow[64];

  const int tid = threadIdx.x;
  if (tid < 64) {
    const int idx = p0 + tid;
    const int pid = (idx < n) ? list[e * kT + idx] : -1;
    ppid[tid] = pid;
    prow[tid] = (pid < 0) ? 0 : pid;
  }
  __syncthreads();

  const float* w2e = w2 + (size_t)e * kH * kF;

  const unsigned short* a_src[2]; const float* b_src[2];
  int sw_[2];
#pragma unroll
  for (int i = 0; i < 2; ++i) {
    const int flat = tid + 256 * i;
    const int row = flat >> 3, u = flat & 7;
    a_src[i] = hmid + (size_t)prow[row] * kF + u * 8;
    b_src[i] = w2e + (size_t)(h0 + row) * kF + u * 8;
    sw_[i] = swz(row, u);
  }

  const int lane = tid & 63, wid = tid >> 6;
  const int wr = wid >> 1, wc = wid & 1;
  const int lr = lane & 15, lq = lane >> 4;

  fx4 acc[2][2];
#pragma unroll
  for (int i = 0; i < 2; ++i)
#pragma unroll
    for (int j = 0; j < 2; ++j) acc[i][j] = (fx4)(0.f);

  auto LOAD = [&](StageO& S, int k0) {
#pragma unroll
    for (int i = 0; i < 2; ++i) {
      S.a[i]    = *reinterpret_cast<const bf16x8*>(a_src[i] + k0);
      S.b[i][0] = *reinterpret_cast<const float4*>(b_src[i] + k0);
      S.b[i][1] = *reinterpret_cast<const float4*>(b_src[i] + k0 + 4);
    }
  };
  auto STORE = [&](const StageO& S, int buf) {
#pragma unroll
    for (int i = 0; i < 2; ++i) {
      *reinterpret_cast<bf16x8*>(&As[buf][sw_[i]]) = S.a[i];
      *reinterpret_cast<bf16x8*>(&Bs[buf][sw_[i]]) = pack8(S.b[i][0], S.b[i][1]);
    }
  };
  auto MFMA_PHASE = [&](int buf) {
    const short* Ab = As[buf]; const short* Bb = Bs[buf];
    __builtin_amdgcn_s_setprio(1);
#pragma unroll
    for (int ks = 0; ks < 2; ++ks) {
      bf16x8 a[2], b[2];
#pragma unroll
      for (int mi = 0; mi < 2; ++mi)
        a[mi] = *reinterpret_cast<const bf16x8*>(&Ab[swz(wr * 32 + mi * 16 + lr, ks * 4 + lq)]);
#pragma unroll
      for (int ni = 0; ni < 2; ++ni)
        b[ni] = *reinterpret_cast<const bf16x8*>(&Bb[swz(wc * 32 + ni * 16 + lr, ks * 4 + lq)]);
#pragma unroll
      for (int mi = 0; mi < 2; ++mi)
#pragma unroll
        for (int ni = 0; ni < 2; ++ni)
          acc[mi][ni] = __builtin_amdgcn_mfma_f32_16x16x32_bf16(a[mi], b[ni], acc[mi][ni], 0, 0, 0);
    }
    __builtin_amdgcn_s_setprio(0);
  };

  StageO R0, R1;
  constexpr int NIT = kF / 64;
  LOAD(R0, 0);
  LOAD(R1, 64);
  STORE(R0, 0);
  __syncthreads();
#pragma unroll 2
  for (int it = 0; it < NIT; ++it) {
    if (it & 1) {
      if (it + 2 < NIT) LOAD(R1, (it + 2) * 64);
      MFMA_PHASE(1);
      if (it + 1 < NIT) STORE(R0, 0);
    } else {
      if (it + 2 < NIT) LOAD(R0, (it + 2) * 64);
      MFMA_PHASE(0);
      if (it + 1 < NIT) STORE(R1, 1);
    }
    __syncthreads();
  }

#pragma unroll
  for (int mi = 0; mi < 2; ++mi)
#pragma unroll
    for (int i = 0; i < 4; ++i) {
      const int row = wr * 32 + mi * 16 + lq * 4 + i;
      const int pid = ppid[row];
      if (pid < 0) continue;
      const int tok = pid >> 1;
      const float w = rw[pid];
      float* op = out + (size_t)tok * kH + h0 + wc * 32 + lr;
#pragma unroll
      for (int ni = 0; ni < 2; ++ni)
        atomicAdd(&op[ni * 16], w * acc[mi][ni][i]);
    }
}

// ---------------------------------------------------------------------------
extern "C" void kernel_launch(void* const* d_in, const int* in_sizes, int n_in,
                              void* d_out, int out_size, void* d_ws,
                              size_t ws_size, hipStream_t stream) {
  (void)in_sizes; (void)n_in; (void)out_size;
  const float* x  = (const float*)d_in[0];  // [1,2048,1024]
  const float* gw = (const float*)d_in[1];  // [8,1024]
  const float* w1 = (const float*)d_in[2];  // [8,3584,1024]
  const float* w2 = (const float*)d_in[3];  // [8,1024,3584]
  const float* w3 = (const float*)d_in[4];  // [8,3584,1024]

  float* out    = (float*)d_out;             // [2048*1024]
  float* logits = out + (size_t)kT * kH;     // [2048*8]

  char* ws = (char*)d_ws;
  int*            cnt  = (int*)(ws + OFF_CNT);
  int*            list = (int*)(ws + OFF_LIST);
  float*          rw   = (float*)(ws + OFF_RW);
  unsigned short* hmid = (unsigned short*)(ws + OFF_HMID);

  hipMemsetAsync(out, 0, (size_t)kT * kH * sizeof(float), stream);
  hipMemsetAsync(cnt, 0, kE * sizeof(int), stream);

  router_kernel<<<kT, 256, 0, stream>>>(x, gw, logits, cnt, list, rw);

  if (ws_size >= WS_NEED) {
    unsigned short* xb  = (unsigned short*)(ws + OFF_XB);
    unsigned short* w1b = (unsigned short*)(ws + OFF_W1B);
    unsigned short* w3b = (unsigned short*)(ws + OFF_W3B);
    unsigned short* w2b = (unsigned short*)(ws + OFF_W2B);

    cast_all_kernel<<<2048, 256, 0, stream>>>(x, w1, w3, w2, xb);

    dim3 g1(kF / 64, kT / 256, kE);    // (56, 8, 8)
    moe_mid_gl<<<g1, 256, 0, stream>>>(xb, w1b, w3b, cnt, list, hmid);

    dim3 g2(kH / 128, kT / 128, kE);   // (8, 16, 8)
    moe_out_gl<<<g2, 256, 0, stream>>>(hmid, w2b, cnt, list, rw, out);
  } else {
    dim3 g1(kF / 64, kT / 64, kE);   // (56, 32, 8)
    moe_mid_mfma<<<g1, 256, 0, stream>>>(x, w1, w3, cnt, list, hmid);

    dim3 g2(kH / 64, kT / 64, kE);   // (16, 32, 8)
    moe_out_mfma<<<g2, 256, 0, stream>>>(hmid, w2, cnt, list, rw, out);
  }
}

// Round 15
// 315.998 us; speedup vs baseline: 1.1954x; 1.1954x over previous
//
#include <hip/hip_runtime.h>
#include <hip/hip_bf16.h>
#include <math.h>

// Problem constants (B=1, S=2048, H=1024, E=8, F=3584, K=2)
namespace {
constexpr int kT = 2048;   // tokens
constexpr int kH = 1024;   // hidden
constexpr int kE = 8;      // experts
constexpr int kF = 3584;   // ffn dim
constexpr int kK = 2;      // top-k

// workspace layout (bytes)
constexpr size_t OFF_CNT  = 0;                                // int[8]
constexpr size_t OFF_LIST = 1024;                             // int[8][2048]
constexpr size_t OFF_RW   = OFF_LIST + sizeof(int) * kE * kT; // float[4096]
constexpr size_t OFF_HMID = 1u << 20;                         // bf16[4096][3584] = 28.7 MB
// fast path: contiguous bf16 mirror  xb | w1b | w3b | w2b
constexpr size_t OFF_XB   = 32u << 20;
constexpr size_t SZ_XB    = (size_t)kT * kH * 2;              // 4 MB
constexpr size_t SZ_W     = (size_t)kE * kF * kH * 2;         // 56 MB
constexpr size_t OFF_W1B  = OFF_XB + SZ_XB;
constexpr size_t OFF_W3B  = OFF_W1B + SZ_W;
constexpr size_t OFF_W2B  = OFF_W3B + SZ_W;
constexpr size_t WS_NEED  = OFF_W2B + SZ_W;                   // ~204 MB

constexpr long NX8  = (long)kT * kH / 8;          // 262,144
constexpr long NW8  = (long)kE * kF * kH / 8;     // 3,670,016
constexpr long TOT8 = NX8 + 3 * NW8;

typedef __attribute__((ext_vector_type(8))) short bf16x8;     // 8 bf16 in 4 VGPRs
typedef __attribute__((ext_vector_type(4))) float fx4;
}

// f32 -> bf16 via compiler intrinsic (emits v_cvt_pk_bf16_f32 pairs)
__device__ __forceinline__ short f2bf_s(float f) {
  union { __hip_bfloat16 h; short s; } u;
  u.h = __float2bfloat16(f);
  return u.s;
}

__device__ __forceinline__ bf16x8 pack8(float4 a, float4 b) {
  bf16x8 r;
  r[0] = f2bf_s(a.x); r[1] = f2bf_s(a.y);
  r[2] = f2bf_s(a.z); r[3] = f2bf_s(a.w);
  r[4] = f2bf_s(b.x); r[5] = f2bf_s(b.y);
  r[6] = f2bf_s(b.z); r[7] = f2bf_s(b.w);
  return r;
}

__device__ __forceinline__ bf16x8 pack8v(fx4 a, fx4 b) {
  bf16x8 r;
  r[0] = f2bf_s(a[0]); r[1] = f2bf_s(a[1]);
  r[2] = f2bf_s(a[2]); r[3] = f2bf_s(a[3]);
  r[4] = f2bf_s(b[0]); r[5] = f2bf_s(b[1]);
  r[6] = f2bf_s(b[2]); r[7] = f2bf_s(b[3]);
  return r;
}

// LDS rows of 64 bf16 (128 B) = 8 x 16B units; XOR unit by (row&7).
// 0 bank conflicts measured (R4-R14). global_load_lds path: LDS dst LINEAR,
// XOR on the per-lane GLOBAL source address (rule #21 pairing), swz() on read.
__device__ __forceinline__ int swz(int row, int u) {
  return row * 64 + ((u ^ (row & 7)) << 3);   // index in shorts
}

// async 16B global->LDS (gfx950); dst = wave-uniform base + lane*16.
__device__ __forceinline__ void gload16(const void* g, void* l) {
  __builtin_amdgcn_global_load_lds(
      (const __attribute__((address_space(1))) void*)g,
      (__attribute__((address_space(3))) void*)l, 16, 0, 0);
}

// ---------------------------------------------------------------------------
// Fused f32 -> bf16 cast (one launch). ~103 us measured = HBM roofline for
// its 676 MB of traffic (107 us at 6.3 TB/s). Do not touch.
// ---------------------------------------------------------------------------
__global__ __launch_bounds__(256) void cast_all_kernel(
    const float* __restrict__ x, const float* __restrict__ w1,
    const float* __restrict__ w3, const float* __restrict__ w2,
    unsigned short* __restrict__ dst) {
  long i = (long)blockIdx.x * blockDim.x + threadIdx.x;
  const long stride = (long)gridDim.x * blockDim.x;
  for (; i < TOT8; i += stride) {
    const float* s; long o;
    if (i < NX8)              { s = x;  o = i; }
    else if (i < NX8 + NW8)   { s = w1; o = i - NX8; }
    else if (i < NX8 + 2*NW8) { s = w3; o = i - NX8 - NW8; }
    else                      { s = w2; o = i - NX8 - 2*NW8; }
    const fx4* sp = reinterpret_cast<const fx4*>(s + o * 8);
    const fx4 v0 = __builtin_nontemporal_load(sp);
    const fx4 v1 = __builtin_nontemporal_load(sp + 1);
    *reinterpret_cast<bf16x8*>(dst + i * 8) = pack8v(v0, v1);
  }
}

// ---------------------------------------------------------------------------
// Router (f32, exact — expert selection must not move).
// ---------------------------------------------------------------------------
__global__ __launch_bounds__(256) void router_kernel(
    const float* __restrict__ x, const float* __restrict__ gw,
    float* __restrict__ logits_out, int* __restrict__ cnt,
    int* __restrict__ list, float* __restrict__ rw) {
  const int t = blockIdx.x;
  const float* xt = x + (size_t)t * kH;
  __shared__ float lg[kE];
  const int wave = threadIdx.x >> 6;
  const int lane = threadIdx.x & 63;
  for (int e = wave; e < kE; e += 4) {
    const float* g = gw + (size_t)e * kH;
    float s = 0.f;
    for (int h = lane; h < kH; h += 64) s += xt[h] * g[h];
#pragma unroll
    for (int off = 32; off > 0; off >>= 1) s += __shfl_down(s, off, 64);
    if (lane == 0) lg[e] = s;
  }
  __syncthreads();
  if (threadIdx.x < kE) logits_out[(size_t)t * kE + threadIdx.x] = lg[threadIdx.x];
  if (threadIdx.x == 0) {
    float m = lg[0];
#pragma unroll
    for (int e = 1; e < kE; ++e) m = fmaxf(m, lg[e]);
    float p[kE];
#pragma unroll
    for (int e = 0; e < kE; ++e) p[e] = expf(lg[e] - m);
    int i0 = 0;
#pragma unroll
    for (int e = 1; e < kE; ++e) if (p[e] > p[i0]) i0 = e;
    int i1 = (i0 == 0) ? 1 : 0;
#pragma unroll
    for (int e = 0; e < kE; ++e)
      if (e != i0 && e != i1 && p[e] > p[i1]) i1 = e;
    const float w0 = p[i0], w1v = p[i1];
    const float inv = 1.f / (w0 + w1v);
    rw[t * kK + 0] = w0 * inv;
    rw[t * kK + 1] = w1v * inv;
    const int s0 = atomicAdd(&cnt[i0], 1);
    list[i0 * kT + s0] = t * kK + 0;
    const int s1 = atomicAdd(&cnt[i1], 1);
    list[i1 * kT + s1] = t * kK + 1;
  }
}

// ===========================================================================
// FAST PATH: counted-vmcnt pipeline (T4), R12 tile configs (best: 317 us).
// This round: ds_read offsets PRECOMPUTED into registers before the K-loop
// (mid VALUBusy was 47% vs MfmaUtil 27% — addressing-bound; swz() was
// recomputed per iter because the buf-switching base defeats hoisting).
// ===========================================================================

// GEMM1: hmid[p,f] = bf16(silu(x.w1)*(x.w3)); block 128p x 64f, BK=64,
// 4 waves (2x2), wave tile 64x32. LDS 64KB (2 buf). 8 gload16/thread/stage.
__global__ __launch_bounds__(256) void moe_mid_gl(
    const unsigned short* __restrict__ xb, const unsigned short* __restrict__ w1b,
    const unsigned short* __restrict__ w3b, const int* __restrict__ cnt,
    const int* __restrict__ list, unsigned short* __restrict__ hmid) {
  const int e = blockIdx.z;
  const int n = cnt[e];
  const int t0 = blockIdx.y * 128;
  if (t0 >= n) return;
  const int f0 = blockIdx.x * 64;

  __shared__ short As[2][128 * 64];
  __shared__ short B1s[2][64 * 64];
  __shared__ short B3s[2][64 * 64];
  __shared__ int ppid[128];
  __shared__ int ptok[128];

  const int tid = threadIdx.x;
  if (tid < 128) {
    const int idx = t0 + tid;
    const int pid = (idx < n) ? list[e * kT + idx] : -1;
    ppid[tid] = pid;
    ptok[tid] = (pid < 0) ? 0 : (pid >> 1);
  }
  __syncthreads();   // drains list loads -> vmcnt 0 baseline for the pipeline

  const unsigned short* w1e = w1b + (size_t)e * kF * kH;
  const unsigned short* w3e = w3b + (size_t)e * kF * kH;

  const unsigned short* a_src[4];
#pragma unroll
  for (int c = 0; c < 4; ++c) {
    const int flat = tid + 256 * c;
    const int row = flat >> 3, u = flat & 7;
    a_src[c] = xb + (size_t)ptok[row] * kH + ((u ^ (row & 7)) * 8);
  }
  const unsigned short* b1_src[2]; const unsigned short* b3_src[2];
#pragma unroll
  for (int c = 0; c < 2; ++c) {
    const int flat = tid + 256 * c;
    const int row = flat >> 3, u = flat & 7;
    const int co = (u ^ (row & 7)) * 8;
    b1_src[c] = w1e + (size_t)(f0 + row) * kH + co;
    b3_src[c] = w3e + (size_t)(f0 + row) * kH + co;
  }

  const int lane = tid & 63, wid = tid >> 6;
  const int wr = wid >> 1, wc = wid & 1;
  const int lr = lane & 15, lq = lane >> 4;

  // Precomputed LDS read offsets (loop-invariant; static-indexed -> registers)
  int aofs[2][4], bofs[2][2];
#pragma unroll
  for (int ks = 0; ks < 2; ++ks) {
#pragma unroll
    for (int mi = 0; mi < 4; ++mi)
      aofs[ks][mi] = swz(wr * 64 + mi * 16 + lr, ks * 4 + lq);
#pragma unroll
    for (int ni = 0; ni < 2; ++ni)
      bofs[ks][ni] = swz(wc * 32 + ni * 16 + lr, ks * 4 + lq);
  }

  fx4 acc1[4][2], acc3[4][2];
#pragma unroll
  for (int i = 0; i < 4; ++i)
#pragma unroll
    for (int j = 0; j < 2; ++j) { acc1[i][j] = (fx4)(0.f); acc3[i][j] = (fx4)(0.f); }

  auto STAGE = [&](int buf, int k0) {
#pragma unroll
    for (int c = 0; c < 4; ++c)
      gload16(a_src[c] + k0, &As[buf][(tid + 256 * c) * 8]);
#pragma unroll
    for (int c = 0; c < 2; ++c) {
      gload16(b1_src[c] + k0, &B1s[buf][(tid + 256 * c) * 8]);
      gload16(b3_src[c] + k0, &B3s[buf][(tid + 256 * c) * 8]);
    }
  };
  auto MFMA_PHASE = [&](int buf) {
    const short* Ab = As[buf]; const short* B1b = B1s[buf]; const short* B3b = B3s[buf];
    __builtin_amdgcn_s_setprio(1);
#pragma unroll
    for (int ks = 0; ks < 2; ++ks) {
      bf16x8 a[4], bb1[2], bb3[2];
#pragma unroll
      for (int mi = 0; mi < 4; ++mi)
        a[mi] = *reinterpret_cast<const bf16x8*>(&Ab[aofs[ks][mi]]);
#pragma unroll
      for (int ni = 0; ni < 2; ++ni) {
        bb1[ni] = *reinterpret_cast<const bf16x8*>(&B1b[bofs[ks][ni]]);
        bb3[ni] = *reinterpret_cast<const bf16x8*>(&B3b[bofs[ks][ni]]);
      }
#pragma unroll
      for (int mi = 0; mi < 4; ++mi)
#pragma unroll
        for (int ni = 0; ni < 2; ++ni) {
          acc1[mi][ni] = __builtin_amdgcn_mfma_f32_16x16x32_bf16(a[mi], bb1[ni], acc1[mi][ni], 0, 0, 0);
          acc3[mi][ni] = __builtin_amdgcn_mfma_f32_16x16x32_bf16(a[mi], bb3[ni], acc3[mi][ni], 0, 0, 0);
        }
    }
    __builtin_amdgcn_s_setprio(0);
  };

  constexpr int NIT = kH / 64;  // 16
  STAGE(0, 0);
  STAGE(1, 64);                 // 16 loads in flight per thread
  for (int it = 0; it < NIT; ++it) {
    const int cur = it & 1;
    if (it + 1 < NIT) asm volatile("s_waitcnt vmcnt(8)" ::: "memory");
    else              asm volatile("s_waitcnt vmcnt(0)" ::: "memory");
    asm volatile("s_barrier" ::: "memory");   // all waves' stage(it) visible
    MFMA_PHASE(cur);
    asm volatile("s_barrier" ::: "memory");   // all waves done reading buf
    if (it + 2 < NIT) STAGE(cur, (it + 2) * 64);
  }

#pragma unroll
  for (int mi = 0; mi < 4; ++mi)
#pragma unroll
    for (int i = 0; i < 4; ++i) {
      const int row = wr * 64 + mi * 16 + lq * 4 + i;
      const int pid = ppid[row];
      if (pid < 0) continue;
#pragma unroll
      for (int ni = 0; ni < 2; ++ni) {
        const int col = f0 + wc * 32 + ni * 16 + lr;
        const float s1 = acc1[mi][ni][i];
        const float s3 = acc3[mi][ni][i];
        const float h = s1 * s3 / (1.f + expf(-s1));  // silu(s1)*s3
        hmid[(size_t)pid * kF + col] = (unsigned short)f2bf_s(h);
      }
    }
}

// GEMM2 (R12 config): out[t,:] += rw[p] * (hmid . w2); 128p x 64h, BK=64,
// 48KB LDS, 6 gload16/thread/stage. 2 commutative f32 atomics per element.
__global__ __launch_bounds__(256) void moe_out_gl(
    const unsigned short* __restrict__ hmid, const unsigned short* __restrict__ w2b,
    const int* __restrict__ cnt, const int* __restrict__ list,
    const float* __restrict__ rw, float* __restrict__ out) {
  const int e = blockIdx.z;
  const int n = cnt[e];
  const int p0 = blockIdx.y * 128;
  if (p0 >= n) return;
  const int h0 = blockIdx.x * 64;

  __shared__ short As[2][128 * 64];
  __shared__ short Bs[2][64 * 64];
  __shared__ int ppid[128];
  __shared__ int prow[128];

  const int tid = threadIdx.x;
  if (tid < 128) {
    const int idx = p0 + tid;
    const int pid = (idx < n) ? list[e * kT + idx] : -1;
    ppid[tid] = pid;
    prow[tid] = (pid < 0) ? 0 : pid;
  }
  __syncthreads();

  const unsigned short* w2e = w2b + (size_t)e * kH * kF;

  const unsigned short* a_src[4];
#pragma unroll
  for (int c = 0; c < 4; ++c) {
    const int flat = tid + 256 * c;
    const int row = flat >> 3, u = flat & 7;
    a_src[c] = hmid + (size_t)prow[row] * kF + ((u ^ (row & 7)) * 8);
  }
  const unsigned short* b_src[2];
#pragma unroll
  for (int c = 0; c < 2; ++c) {
    const int flat = tid + 256 * c;
    const int row = flat >> 3, u = flat & 7;
    b_src[c] = w2e + (size_t)(h0 + row) * kF + ((u ^ (row & 7)) * 8);
  }

  const int lane = tid & 63, wid = tid >> 6;
  const int wr = wid >> 1, wc = wid & 1;
  const int lr = lane & 15, lq = lane >> 4;

  // Precomputed LDS read offsets
  int aofs[2][4], bofs[2][2];
#pragma unroll
  for (int ks = 0; ks < 2; ++ks) {
#pragma unroll
    for (int mi = 0; mi < 4; ++mi)
      aofs[ks][mi] = swz(wr * 64 + mi * 16 + lr, ks * 4 + lq);
#pragma unroll
    for (int ni = 0; ni < 2; ++ni)
      bofs[ks][ni] = swz(wc * 32 + ni * 16 + lr, ks * 4 + lq);
  }

  fx4 acc[4][2];
#pragma unroll
  for (int i = 0; i < 4; ++i)
#pragma unroll
    for (int j = 0; j < 2; ++j) acc[i][j] = (fx4)(0.f);

  auto STAGE = [&](int buf, int k0) {
#pragma unroll
    for (int c = 0; c < 4; ++c)
      gload16(a_src[c] + k0, &As[buf][(tid + 256 * c) * 8]);
#pragma unroll
    for (int c = 0; c < 2; ++c)
      gload16(b_src[c] + k0, &Bs[buf][(tid + 256 * c) * 8]);
  };
  auto MFMA_PHASE = [&](int buf) {
    const short* Ab = As[buf]; const short* Bb = Bs[buf];
    __builtin_amdgcn_s_setprio(1);
#pragma unroll
    for (int ks = 0; ks < 2; ++ks) {
      bf16x8 a[4], b[2];
#pragma unroll
      for (int mi = 0; mi < 4; ++mi)
        a[mi] = *reinterpret_cast<const bf16x8*>(&Ab[aofs[ks][mi]]);
#pragma unroll
      for (int ni = 0; ni < 2; ++ni)
        b[ni] = *reinterpret_cast<const bf16x8*>(&Bb[bofs[ks][ni]]);
#pragma unroll
      for (int mi = 0; mi < 4; ++mi)
#pragma unroll
        for (int ni = 0; ni < 2; ++ni)
          acc[mi][ni] = __builtin_amdgcn_mfma_f32_16x16x32_bf16(a[mi], b[ni], acc[mi][ni], 0, 0, 0);
    }
    __builtin_amdgcn_s_setprio(0);
  };

  constexpr int NIT = kF / 64;  // 56
  STAGE(0, 0);
  STAGE(1, 64);                 // 12 loads in flight per thread
  for (int it = 0; it < NIT; ++it) {
    const int cur = it & 1;
    if (it + 1 < NIT) asm volatile("s_waitcnt vmcnt(6)" ::: "memory");
    else              asm volatile("s_waitcnt vmcnt(0)" ::: "memory");
    asm volatile("s_barrier" ::: "memory");
    MFMA_PHASE(cur);
    asm volatile("s_barrier" ::: "memory");
    if (it + 2 < NIT) STAGE(cur, (it + 2) * 64);
  }

#pragma unroll
  for (int mi = 0; mi < 4; ++mi)
#pragma unroll
    for (int i = 0; i < 4; ++i) {
      const int row = wr * 64 + mi * 16 + lq * 4 + i;
      const int pid = ppid[row];
      if (pid < 0) continue;
      const int tok = pid >> 1;
      const float w = rw[pid];
      float* op = out + (size_t)tok * kH + h0 + wc * 32 + lr;
#pragma unroll
      for (int ni = 0; ni < 2; ++ni)
        atomicAdd(&op[ni * 16], w * acc[mi][ni][i]);
    }
}

// ===========================================================================
// FALLBACK PATH (ws too small): R7 kernels, known-good 342 us.
// ===========================================================================
struct StageM { float4 a[2][2], b1[2][2], b3[2][2]; };

__global__ __launch_bounds__(256) void moe_mid_mfma(
    const float* __restrict__ x, const float* __restrict__ w1,
    const float* __restrict__ w3, const int* __restrict__ cnt,
    const int* __restrict__ list, unsigned short* __restrict__ hmid) {
  const int e = blockIdx.z;
  const int n = cnt[e];
  const int t0 = blockIdx.y * 64;
  if (t0 >= n) return;
  const int f0 = blockIdx.x * 64;

  __shared__ short As[2][64 * 64];
  __shared__ short B1s[2][64 * 64];
  __shared__ short B3s[2][64 * 64];
  __shared__ int ppid[64];
  __shared__ int ptok[64];

  const int tid = threadIdx.x;
  if (tid < 64) {
    const int idx = t0 + tid;
    const int pid = (idx < n) ? list[e * kT + idx] : -1;
    ppid[tid] = pid;
    ptok[tid] = (pid < 0) ? 0 : (pid >> 1);
  }
  __syncthreads();

  const float* w1e = w1 + (size_t)e * kF * kH;
  const float* w3e = w3 + (size_t)e * kF * kH;

  const float* a_src[2]; const float* b1_src[2]; const float* b3_src[2];
  int sw_[2];
#pragma unroll
  for (int i = 0; i < 2; ++i) {
    const int flat = tid + 256 * i;
    const int row = flat >> 3, u = flat & 7;
    a_src[i]  = x + (size_t)ptok[row] * kH + u * 8;
    b1_src[i] = w1e + (size_t)(f0 + row) * kH + u * 8;
    b3_src[i] = w3e + (size_t)(f0 + row) * kH + u * 8;
    sw_[i] = swz(row, u);
  }

  const int lane = tid & 63, wid = tid >> 6;
  const int wr = wid >> 1, wc = wid & 1;
  const int lr = lane & 15, lq = lane >> 4;

  fx4 acc1[2][2], acc3[2][2];
#pragma unroll
  for (int i = 0; i < 2; ++i)
#pragma unroll
    for (int j = 0; j < 2; ++j) { acc1[i][j] = (fx4)(0.f); acc3[i][j] = (fx4)(0.f); }

  auto LOAD = [&](StageM& S, int k0) {
#pragma unroll
    for (int i = 0; i < 2; ++i) {
      S.a[i][0]  = *reinterpret_cast<const float4*>(a_src[i] + k0);
      S.a[i][1]  = *reinterpret_cast<const float4*>(a_src[i] + k0 + 4);
      S.b1[i][0] = *reinterpret_cast<const float4*>(b1_src[i] + k0);
      S.b1[i][1] = *reinterpret_cast<const float4*>(b1_src[i] + k0 + 4);
      S.b3[i][0] = *reinterpret_cast<const float4*>(b3_src[i] + k0);
      S.b3[i][1] = *reinterpret_cast<const float4*>(b3_src[i] + k0 + 4);
    }
  };
  auto STORE = [&](const StageM& S, int buf) {
#pragma unroll
    for (int i = 0; i < 2; ++i) {
      *reinterpret_cast<bf16x8*>(&As[buf][sw_[i]])  = pack8(S.a[i][0], S.a[i][1]);
      *reinterpret_cast<bf16x8*>(&B1s[buf][sw_[i]]) = pack8(S.b1[i][0], S.b1[i][1]);
      *reinterpret_cast<bf16x8*>(&B3s[buf][sw_[i]]) = pack8(S.b3[i][0], S.b3[i][1]);
    }
  };
  auto MFMA_PHASE = [&](int buf) {
    const short* Ab = As[buf]; const short* B1b = B1s[buf]; const short* B3b = B3s[buf];
    __builtin_amdgcn_s_setprio(1);
#pragma unroll
    for (int ks = 0; ks < 2; ++ks) {
      bf16x8 a[2], bb1[2], bb3[2];
#pragma unroll
      for (int mi = 0; mi < 2; ++mi)
        a[mi] = *reinterpret_cast<const bf16x8*>(&Ab[swz(wr * 32 + mi * 16 + lr, ks * 4 + lq)]);
#pragma unroll
      for (int ni = 0; ni < 2; ++ni) {
        bb1[ni] = *reinterpret_cast<const bf16x8*>(&B1b[swz(wc * 32 + ni * 16 + lr, ks * 4 + lq)]);
        bb3[ni] = *reinterpret_cast<const bf16x8*>(&B3b[swz(wc * 32 + ni * 16 + lr, ks * 4 + lq)]);
      }
#pragma unroll
      for (int mi = 0; mi < 2; ++mi)
#pragma unroll
        for (int ni = 0; ni < 2; ++ni) {
          acc1[mi][ni] = __builtin_amdgcn_mfma_f32_16x16x32_bf16(a[mi], bb1[ni], acc1[mi][ni], 0, 0, 0);
          acc3[mi][ni] = __builtin_amdgcn_mfma_f32_16x16x32_bf16(a[mi], bb3[ni], acc3[mi][ni], 0, 0, 0);
        }
    }
    __builtin_amdgcn_s_setprio(0);
  };

  StageM R0, R1;
  constexpr int NIT = kH / 64;
  LOAD(R0, 0);
  LOAD(R1, 64);
  STORE(R0, 0);
  __syncthreads();
#pragma unroll 2
  for (int it = 0; it < NIT; ++it) {
    if (it & 1) {
      if (it + 2 < NIT) LOAD(R1, (it + 2) * 64);
      MFMA_PHASE(1);
      if (it + 1 < NIT) STORE(R0, 0);
    } else {
      if (it + 2 < NIT) LOAD(R0, (it + 2) * 64);
      MFMA_PHASE(0);
      if (it + 1 < NIT) STORE(R1, 1);
    }
    __syncthreads();
  }

#pragma unroll
  for (int mi = 0; mi < 2; ++mi)
#pragma unroll
    for (int i = 0; i < 4; ++i) {
      const int row = wr * 32 + mi * 16 + lq * 4 + i;
      const int pid = ppid[row];
      if (pid < 0) continue;
#pragma unroll
      for (int ni = 0; ni < 2; ++ni) {
        const int col = f0 + wc * 32 + ni * 16 + lr;
        const float s1 = acc1[mi][ni][i];
        const float s3 = acc3[mi][ni][i];
        const float h = s1 * s3 / (1.f + expf(-s1));
        hmid[(size_t)pid * kF + col] = (unsigned short)f2bf_s(h);
      }
    }
}

struct StageO { bf16x8 a[2]; float4 b[2][2]; };

__global__ __launch_bounds__(256) void moe_out_mfma(
    const unsigned short* __restrict__ hmid, const float* __restrict__ w2,
    const int* __restrict__ cnt, const int* __restrict__ list,
    const float* __restrict__ rw, float* __restrict__ out) {
  const int e = blockIdx.z;
  const int n = cnt[e];
  const int p0 = blockIdx.y * 64;
  if (p0 >= n) return;
  const int h0 = blockIdx.x * 64;

  __shared__ short As[2][64 * 64];
  __shared__ short Bs[2][64 * 64];
  __shared__ int ppid[64];
  __shared__ int prow[64];

  const int tid = threadIdx.x;
  if (tid < 64) {
    const int idx = p0 + tid;
    const int pid = (idx < n) ? list[e * kT + idx] : -1;
    ppid[tid] = pid;
    prow[tid] = (pid < 0) ? 0 : pid;
  }
  __syncthreads();

  const float* w2e = w2 + (size_t)e * kH * kF;

  const unsigned short* a_src[2]; const float* b_src[2];
  int sw_[2];
#pragma unroll
  for (int i = 0; i < 2; ++i) {
    const int flat = tid + 256 * i;
    const int row = flat >> 3, u = flat & 7;
    a_src[i] = hmid + (size_t)prow[row] * kF + u * 8;
    b_src[i] = w2e + (size_t)(h0 + row) * kF + u * 8;
    sw_[i] = swz(row, u);
  }

  const int lane = tid & 63, wid = tid >> 6;
  const int wr = wid >> 1, wc = wid & 1;
  const int lr = lane & 15, lq = lane >> 4;

  fx4 acc[2][2];
#pragma unroll
  for (int i = 0; i < 2; ++i)
#pragma unroll
    for (int j = 0; j < 2; ++j) acc[i][j] = (fx4)(0.f);

  auto LOAD = [&](StageO& S, int k0) {
#pragma unroll
    for (int i = 0; i < 2; ++i) {
      S.a[i]    = *reinterpret_cast<const bf16x8*>(a_src[i] + k0);
      S.b[i][0] = *reinterpret_cast<const float4*>(b_src[i] + k0);
      S.b[i][1] = *reinterpret_cast<const float4*>(b_src[i] + k0 + 4);
    }
  };
  auto STORE = [&](const StageO& S, int buf) {
#pragma unroll
    for (int i = 0; i < 2; ++i) {
      *reinterpret_cast<bf16x8*>(&As[buf][sw_[i]]) = S.a[i];
      *reinterpret_cast<bf16x8*>(&Bs[buf][sw_[i]]) = pack8(S.b[i][0], S.b[i][1]);
    }
  };
  auto MFMA_PHASE = [&](int buf) {
    const short* Ab = As[buf]; const short* Bb = Bs[buf];
    __builtin_amdgcn_s_setprio(1);
#pragma unroll
    for (int ks = 0; ks < 2; ++ks) {
      bf16x8 a[2], b[2];
#pragma unroll
      for (int mi = 0; mi < 2; ++mi)
        a[mi] = *reinterpret_cast<const bf16x8*>(&Ab[swz(wr * 32 + mi * 16 + lr, ks * 4 + lq)]);
#pragma unroll
      for (int ni = 0; ni < 2; ++ni)
        b[ni] = *reinterpret_cast<const bf16x8*>(&Bb[swz(wc * 32 + ni * 16 + lr, ks * 4 + lq)]);
#pragma unroll
      for (int mi = 0; mi < 2; ++mi)
#pragma unroll
        for (int ni = 0; ni < 2; ++ni)
          acc[mi][ni] = __builtin_amdgcn_mfma_f32_16x16x32_bf16(a[mi], b[ni], acc[mi][ni], 0, 0, 0);
    }
    __builtin_amdgcn_s_setprio(0);
  };

  StageO R0, R1;
  constexpr int NIT = kF / 64;
  LOAD(R0, 0);
  LOAD(R1, 64);
  STORE(R0, 0);
  __syncthreads();
#pragma unroll 2
  for (int it = 0; it < NIT; ++it) {
    if (it & 1) {
      if (it + 2 < NIT) LOAD(R1, (it + 2) * 64);
      MFMA_PHASE(1);
      if (it + 1 < NIT) STORE(R0, 0);
    } else {
      if (it + 2 < NIT) LOAD(R0, (it + 2) * 64);
      MFMA_PHASE(0);
      if (it + 1 < NIT) STORE(R1, 1);
    }
    __syncthreads();
  }

#pragma unroll
  for (int mi = 0; mi < 2; ++mi)
#pragma unroll
    for (int i = 0; i < 4; ++i) {
      const int row = wr * 32 + mi * 16 + lq * 4 + i;
      const int pid = ppid[row];
      if (pid < 0) continue;
      const int tok = pid >> 1;
      const float w = rw[pid];
      float* op = out + (size_t)tok * kH + h0 + wc * 32 + lr;
#pragma unroll
      for (int ni = 0; ni < 2; ++ni)
        atomicAdd(&op[ni * 16], w * acc[mi][ni][i]);
    }
}

// ---------------------------------------------------------------------------
extern "C" void kernel_launch(void* const* d_in, const int* in_sizes, int n_in,
                              void* d_out, int out_size, void* d_ws,
                              size_t ws_size, hipStream_t stream) {
  (void)in_sizes; (void)n_in; (void)out_size;
  const float* x  = (const float*)d_in[0];  // [1,2048,1024]
  const float* gw = (const float*)d_in[1];  // [8,1024]
  const float* w1 = (const float*)d_in[2];  // [8,3584,1024]
  const float* w2 = (const float*)d_in[3];  // [8,1024,3584]
  const float* w3 = (const float*)d_in[4];  // [8,3584,1024]

  float* out    = (float*)d_out;             // [2048*1024]
  float* logits = out + (size_t)kT * kH;     // [2048*8]

  char* ws = (char*)d_ws;
  int*            cnt  = (int*)(ws + OFF_CNT);
  int*            list = (int*)(ws + OFF_LIST);
  float*          rw   = (float*)(ws + OFF_RW);
  unsigned short* hmid = (unsigned short*)(ws + OFF_HMID);

  hipMemsetAsync(out, 0, (size_t)kT * kH * sizeof(float), stream);
  hipMemsetAsync(cnt, 0, kE * sizeof(int), stream);

  router_kernel<<<kT, 256, 0, stream>>>(x, gw, logits, cnt, list, rw);

  if (ws_size >= WS_NEED) {
    unsigned short* xb  = (unsigned short*)(ws + OFF_XB);
    unsigned short* w1b = (unsigned short*)(ws + OFF_W1B);
    unsigned short* w3b = (unsigned short*)(ws + OFF_W3B);
    unsigned short* w2b = (unsigned short*)(ws + OFF_W2B);

    cast_all_kernel<<<2048, 256, 0, stream>>>(x, w1, w3, w2, xb);

    dim3 g1(kF / 64, kT / 128, kE);   // (56, 16, 8)
    moe_mid_gl<<<g1, 256, 0, stream>>>(xb, w1b, w3b, cnt, list, hmid);

    dim3 g2(kH / 64, kT / 128, kE);   // (16, 16, 8)
    moe_out_gl<<<g2, 256, 0, stream>>>(hmid, w2b, cnt, list, rw, out);
  } else {
    dim3 g1(kF / 64, kT / 64, kE);   // (56, 32, 8)
    moe_mid_mfma<<<g1, 256, 0, stream>>>(x, w1, w3, cnt, list, hmid);

    dim3 g2(kH / 64, kT / 64, kE);   // (16, 32, 8)
    moe_out_mfma<<<g2, 256, 0, stream>>>(hmid, w2, cnt, list, rw, out);
  }
}

// Round 16
// 312.496 us; speedup vs baseline: 1.2088x; 1.0112x over previous
//
#include <hip/hip_runtime.h>
#include <hip/hip_bf16.h>
#include <math.h>

// Problem constants (B=1, S=2048, H=1024, E=8, F=3584, K=2)
namespace {
constexpr int kT = 2048;   // tokens
constexpr int kH = 1024;   // hidden
constexpr int kE = 8;      // experts
constexpr int kF = 3584;   // ffn dim
constexpr int kK = 2;      // top-k

// workspace layout (bytes)
constexpr size_t OFF_CNT  = 0;                                // int[8]
constexpr size_t OFF_LIST = 1024;                             // int[8][2048]
constexpr size_t OFF_RW   = OFF_LIST + sizeof(int) * kE * kT; // float[4096]
constexpr size_t OFF_HMID = 1u << 20;                         // bf16[4096][3584] = 28.7 MB
// fast path: contiguous bf16 mirror  xb | w1b | w3b | w2b
constexpr size_t OFF_XB   = 32u << 20;
constexpr size_t SZ_XB    = (size_t)kT * kH * 2;              // 4 MB
constexpr size_t SZ_W     = (size_t)kE * kF * kH * 2;         // 56 MB
constexpr size_t OFF_W1B  = OFF_XB + SZ_XB;
constexpr size_t OFF_W3B  = OFF_W1B + SZ_W;
constexpr size_t OFF_W2B  = OFF_W3B + SZ_W;
constexpr size_t WS_NEED  = OFF_W2B + SZ_W;                   // ~204 MB

constexpr long NX8  = (long)kT * kH / 8;          // 262,144
constexpr long NW8  = (long)kE * kF * kH / 8;     // 3,670,016
constexpr long TOT8 = NX8 + 3 * NW8;

typedef __attribute__((ext_vector_type(8))) short bf16x8;     // 8 bf16 in 4 VGPRs
typedef __attribute__((ext_vector_type(4))) float fx4;
}

// f32 -> bf16 via compiler intrinsic (emits v_cvt_pk_bf16_f32 pairs)
__device__ __forceinline__ short f2bf_s(float f) {
  union { __hip_bfloat16 h; short s; } u;
  u.h = __float2bfloat16(f);
  return u.s;
}

__device__ __forceinline__ bf16x8 pack8(float4 a, float4 b) {
  bf16x8 r;
  r[0] = f2bf_s(a.x); r[1] = f2bf_s(a.y);
  r[2] = f2bf_s(a.z); r[3] = f2bf_s(a.w);
  r[4] = f2bf_s(b.x); r[5] = f2bf_s(b.y);
  r[6] = f2bf_s(b.z); r[7] = f2bf_s(b.w);
  return r;
}

__device__ __forceinline__ bf16x8 pack8v(fx4 a, fx4 b) {
  bf16x8 r;
  r[0] = f2bf_s(a[0]); r[1] = f2bf_s(a[1]);
  r[2] = f2bf_s(a[2]); r[3] = f2bf_s(a[3]);
  r[4] = f2bf_s(b[0]); r[5] = f2bf_s(b[1]);
  r[6] = f2bf_s(b[2]); r[7] = f2bf_s(b[3]);
  return r;
}

// BK=64 rows (128 B = 8 x 16B units): XOR unit by (row&7). 0 conflicts
// measured (R4-R15). Used by out-GEMM and fallback.
__device__ __forceinline__ int swz(int row, int u) {
  return row * 64 + ((u ^ (row & 7)) << 3);   // index in shorts
}

// BK=32 rows (64 B = 4 x 16B units): XOR unit by ((row>>1)&3). 16-lane
// fragment reads (rows r..r+15, fixed u) then alias only 2-way (free, m136).
// Same involution applied to the pre-swizzled global source (rule #21).
__device__ __forceinline__ int swz32(int row, int u) {
  return row * 32 + ((u ^ ((row >> 1) & 3)) << 3);   // index in shorts
}

// async 16B global->LDS (gfx950); dst = wave-uniform base + lane*16.
__device__ __forceinline__ void gload16(const void* g, void* l) {
  __builtin_amdgcn_global_load_lds(
      (const __attribute__((address_space(1))) void*)g,
      (__attribute__((address_space(3))) void*)l, 16, 0, 0);
}

// ---------------------------------------------------------------------------
// Fused f32 -> bf16 cast (one launch). ~103 us measured = HBM roofline for
// its 676 MB of traffic (107 us at 6.3 TB/s). Do not touch.
// ---------------------------------------------------------------------------
__global__ __launch_bounds__(256) void cast_all_kernel(
    const float* __restrict__ x, const float* __restrict__ w1,
    const float* __restrict__ w3, const float* __restrict__ w2,
    unsigned short* __restrict__ dst) {
  long i = (long)blockIdx.x * blockDim.x + threadIdx.x;
  const long stride = (long)gridDim.x * blockDim.x;
  for (; i < TOT8; i += stride) {
    const float* s; long o;
    if (i < NX8)              { s = x;  o = i; }
    else if (i < NX8 + NW8)   { s = w1; o = i - NX8; }
    else if (i < NX8 + 2*NW8) { s = w3; o = i - NX8 - NW8; }
    else                      { s = w2; o = i - NX8 - 2*NW8; }
    const fx4* sp = reinterpret_cast<const fx4*>(s + o * 8);
    const fx4 v0 = __builtin_nontemporal_load(sp);
    const fx4 v1 = __builtin_nontemporal_load(sp + 1);
    *reinterpret_cast<bf16x8*>(dst + i * 8) = pack8v(v0, v1);
  }
}

// ---------------------------------------------------------------------------
// Router (f32, exact — expert selection must not move).
// ---------------------------------------------------------------------------
__global__ __launch_bounds__(256) void router_kernel(
    const float* __restrict__ x, const float* __restrict__ gw,
    float* __restrict__ logits_out, int* __restrict__ cnt,
    int* __restrict__ list, float* __restrict__ rw) {
  const int t = blockIdx.x;
  const float* xt = x + (size_t)t * kH;
  __shared__ float lg[kE];
  const int wave = threadIdx.x >> 6;
  const int lane = threadIdx.x & 63;
  for (int e = wave; e < kE; e += 4) {
    const float* g = gw + (size_t)e * kH;
    float s = 0.f;
    for (int h = lane; h < kH; h += 64) s += xt[h] * g[h];
#pragma unroll
    for (int off = 32; off > 0; off >>= 1) s += __shfl_down(s, off, 64);
    if (lane == 0) lg[e] = s;
  }
  __syncthreads();
  if (threadIdx.x < kE) logits_out[(size_t)t * kE + threadIdx.x] = lg[threadIdx.x];
  if (threadIdx.x == 0) {
    float m = lg[0];
#pragma unroll
    for (int e = 1; e < kE; ++e) m = fmaxf(m, lg[e]);
    float p[kE];
#pragma unroll
    for (int e = 0; e < kE; ++e) p[e] = expf(lg[e] - m);
    int i0 = 0;
#pragma unroll
    for (int e = 1; e < kE; ++e) if (p[e] > p[i0]) i0 = e;
    int i1 = (i0 == 0) ? 1 : 0;
#pragma unroll
    for (int e = 0; e < kE; ++e)
      if (e != i0 && e != i1 && p[e] > p[i1]) i1 = e;
    const float w0 = p[i0], w1v = p[i1];
    const float inv = 1.f / (w0 + w1v);
    rw[t * kK + 0] = w0 * inv;
    rw[t * kK + 1] = w1v * inv;
    const int s0 = atomicAdd(&cnt[i0], 1);
    list[i0 * kT + s0] = t * kK + 0;
    const int s1 = atomicAdd(&cnt[i1], 1);
    list[i1 * kT + s1] = t * kK + 1;
  }
}

// ===========================================================================
// FAST PATH
// ===========================================================================

// GEMM1 (RE-PIPED this round): BK 64->32, 3-buffer stage-ahead-3.
// Per-buf LDS 16KB x3 = 48KB -> 3 blocks/CU (was ~2 at 64KB); 12 loads in
// flight -> vmcnt(8) steady state. Cross-block TLP covers per-block barriers
// (m114; R14 showed 1 block/CU is fatal, so buy occupancy, not tile size).
__global__ __launch_bounds__(256) void moe_mid_gl(
    const unsigned short* __restrict__ xb, const unsigned short* __restrict__ w1b,
    const unsigned short* __restrict__ w3b, const int* __restrict__ cnt,
    const int* __restrict__ list, unsigned short* __restrict__ hmid) {
  const int e = blockIdx.z;
  const int n = cnt[e];
  const int t0 = blockIdx.y * 128;
  if (t0 >= n) return;
  const int f0 = blockIdx.x * 64;

  __shared__ short As[3][128 * 32];   // 8 KB each
  __shared__ short B1s[3][64 * 32];   // 4 KB each
  __shared__ short B3s[3][64 * 32];
  __shared__ int ppid[128];
  __shared__ int ptok[128];

  const int tid = threadIdx.x;
  if (tid < 128) {
    const int idx = t0 + tid;
    const int pid = (idx < n) ? list[e * kT + idx] : -1;
    ppid[tid] = pid;
    ptok[tid] = (pid < 0) ? 0 : (pid >> 1);
  }
  __syncthreads();   // drains list loads -> vmcnt 0 baseline

  const unsigned short* w1e = w1b + (size_t)e * kF * kH;
  const unsigned short* w3e = w3b + (size_t)e * kF * kH;

  // staging maps: A 128 rows x 4 units = 512 slots (2/thread); B 256 (1/thread)
  const unsigned short* a_src[2];
#pragma unroll
  for (int c = 0; c < 2; ++c) {
    const int flat = tid + 256 * c;
    const int row = flat >> 2, u = flat & 3;
    a_src[c] = xb + (size_t)ptok[row] * kH + ((u ^ ((row >> 1) & 3)) * 8);
  }
  const unsigned short* b1_src;
  const unsigned short* b3_src;
  {
    const int row = tid >> 2, u = tid & 3;
    const int co = (u ^ ((row >> 1) & 3)) * 8;
    b1_src = w1e + (size_t)(f0 + row) * kH + co;
    b3_src = w3e + (size_t)(f0 + row) * kH + co;
  }

  const int lane = tid & 63, wid = tid >> 6;
  const int wr = wid >> 1, wc = wid & 1;
  const int lr = lane & 15, lq = lane >> 4;

  // Precomputed LDS read offsets (loop-invariant)
  int aofs[4], bofs[2];
#pragma unroll
  for (int mi = 0; mi < 4; ++mi)
    aofs[mi] = swz32(wr * 64 + mi * 16 + lr, lq);
#pragma unroll
  for (int ni = 0; ni < 2; ++ni)
    bofs[ni] = swz32(wc * 32 + ni * 16 + lr, lq);

  fx4 acc1[4][2], acc3[4][2];
#pragma unroll
  for (int i = 0; i < 4; ++i)
#pragma unroll
    for (int j = 0; j < 2; ++j) { acc1[i][j] = (fx4)(0.f); acc3[i][j] = (fx4)(0.f); }

  auto STAGE = [&](int buf, int k0) {   // 4 gload16 per thread
#pragma unroll
    for (int c = 0; c < 2; ++c)
      gload16(a_src[c] + k0, &As[buf][(tid + 256 * c) * 8]);
    gload16(b1_src + k0, &B1s[buf][tid * 8]);
    gload16(b3_src + k0, &B3s[buf][tid * 8]);
  };
  auto MFMA_PHASE = [&](int buf) {      // 16 MFMA per wave
    const short* Ab = As[buf]; const short* B1b = B1s[buf]; const short* B3b = B3s[buf];
    __builtin_amdgcn_s_setprio(1);
    bf16x8 a[4], bb1[2], bb3[2];
#pragma unroll
    for (int mi = 0; mi < 4; ++mi)
      a[mi] = *reinterpret_cast<const bf16x8*>(&Ab[aofs[mi]]);
#pragma unroll
    for (int ni = 0; ni < 2; ++ni) {
      bb1[ni] = *reinterpret_cast<const bf16x8*>(&B1b[bofs[ni]]);
      bb3[ni] = *reinterpret_cast<const bf16x8*>(&B3b[bofs[ni]]);
    }
#pragma unroll
    for (int mi = 0; mi < 4; ++mi)
#pragma unroll
      for (int ni = 0; ni < 2; ++ni) {
        acc1[mi][ni] = __builtin_amdgcn_mfma_f32_16x16x32_bf16(a[mi], bb1[ni], acc1[mi][ni], 0, 0, 0);
        acc3[mi][ni] = __builtin_amdgcn_mfma_f32_16x16x32_bf16(a[mi], bb3[ni], acc3[mi][ni], 0, 0, 0);
      }
    __builtin_amdgcn_s_setprio(0);
  };

  constexpr int NIT = kH / 32;  // 32
  STAGE(0, 0);
  STAGE(1, 32);
  STAGE(2, 64);                 // 12 loads in flight per thread
  int buf = 0;
  for (int it = 0; it < NIT; ++it) {
    // wait for stage(it); stages it+1, it+2 (8 loads) stay in flight
    if (it < NIT - 2)       asm volatile("s_waitcnt vmcnt(8)" ::: "memory");
    else if (it == NIT - 2) asm volatile("s_waitcnt vmcnt(4)" ::: "memory");
    else                    asm volatile("s_waitcnt vmcnt(0)" ::: "memory");
    asm volatile("s_barrier" ::: "memory");   // stage(it) visible to all waves
    MFMA_PHASE(buf);
    asm volatile("s_barrier" ::: "memory");   // all waves done reading buf
    if (it + 3 < NIT) STAGE(buf, (it + 3) * 32);
    buf = (buf == 2) ? 0 : buf + 1;
  }

#pragma unroll
  for (int mi = 0; mi < 4; ++mi)
#pragma unroll
    for (int i = 0; i < 4; ++i) {
      const int row = wr * 64 + mi * 16 + lq * 4 + i;
      const int pid = ppid[row];
      if (pid < 0) continue;
#pragma unroll
      for (int ni = 0; ni < 2; ++ni) {
        const int col = f0 + wc * 32 + ni * 16 + lr;
        const float s1 = acc1[mi][ni][i];
        const float s3 = acc3[mi][ni][i];
        const float h = s1 * s3 / (1.f + expf(-s1));  // silu(s1)*s3
        hmid[(size_t)pid * kF + col] = (unsigned short)f2bf_s(h);
      }
    }
}

// GEMM2 (R12/R15 config — control): out[t,:] += rw[p] * (hmid . w2);
// 128p x 64h, BK=64, 48KB LDS, counted vmcnt(6). 2 commutative atomics/elem.
__global__ __launch_bounds__(256) void moe_out_gl(
    const unsigned short* __restrict__ hmid, const unsigned short* __restrict__ w2b,
    const int* __restrict__ cnt, const int* __restrict__ list,
    const float* __restrict__ rw, float* __restrict__ out) {
  const int e = blockIdx.z;
  const int n = cnt[e];
  const int p0 = blockIdx.y * 128;
  if (p0 >= n) return;
  const int h0 = blockIdx.x * 64;

  __shared__ short As[2][128 * 64];
  __shared__ short Bs[2][64 * 64];
  __shared__ int ppid[128];
  __shared__ int prow[128];

  const int tid = threadIdx.x;
  if (tid < 128) {
    const int idx = p0 + tid;
    const int pid = (idx < n) ? list[e * kT + idx] : -1;
    ppid[tid] = pid;
    prow[tid] = (pid < 0) ? 0 : pid;
  }
  __syncthreads();

  const unsigned short* w2e = w2b + (size_t)e * kH * kF;

  const unsigned short* a_src[4];
#pragma unroll
  for (int c = 0; c < 4; ++c) {
    const int flat = tid + 256 * c;
    const int row = flat >> 3, u = flat & 7;
    a_src[c] = hmid + (size_t)prow[row] * kF + ((u ^ (row & 7)) * 8);
  }
  const unsigned short* b_src[2];
#pragma unroll
  for (int c = 0; c < 2; ++c) {
    const int flat = tid + 256 * c;
    const int row = flat >> 3, u = flat & 7;
    b_src[c] = w2e + (size_t)(h0 + row) * kF + ((u ^ (row & 7)) * 8);
  }

  const int lane = tid & 63, wid = tid >> 6;
  const int wr = wid >> 1, wc = wid & 1;
  const int lr = lane & 15, lq = lane >> 4;

  int aofs[2][4], bofs[2][2];
#pragma unroll
  for (int ks = 0; ks < 2; ++ks) {
#pragma unroll
    for (int mi = 0; mi < 4; ++mi)
      aofs[ks][mi] = swz(wr * 64 + mi * 16 + lr, ks * 4 + lq);
#pragma unroll
    for (int ni = 0; ni < 2; ++ni)
      bofs[ks][ni] = swz(wc * 32 + ni * 16 + lr, ks * 4 + lq);
  }

  fx4 acc[4][2];
#pragma unroll
  for (int i = 0; i < 4; ++i)
#pragma unroll
    for (int j = 0; j < 2; ++j) acc[i][j] = (fx4)(0.f);

  auto STAGE = [&](int buf, int k0) {
#pragma unroll
    for (int c = 0; c < 4; ++c)
      gload16(a_src[c] + k0, &As[buf][(tid + 256 * c) * 8]);
#pragma unroll
    for (int c = 0; c < 2; ++c)
      gload16(b_src[c] + k0, &Bs[buf][(tid + 256 * c) * 8]);
  };
  auto MFMA_PHASE = [&](int buf) {
    const short* Ab = As[buf]; const short* Bb = Bs[buf];
    __builtin_amdgcn_s_setprio(1);
#pragma unroll
    for (int ks = 0; ks < 2; ++ks) {
      bf16x8 a[4], b[2];
#pragma unroll
      for (int mi = 0; mi < 4; ++mi)
        a[mi] = *reinterpret_cast<const bf16x8*>(&Ab[aofs[ks][mi]]);
#pragma unroll
      for (int ni = 0; ni < 2; ++ni)
        b[ni] = *reinterpret_cast<const bf16x8*>(&Bb[bofs[ks][ni]]);
#pragma unroll
      for (int mi = 0; mi < 4; ++mi)
#pragma unroll
        for (int ni = 0; ni < 2; ++ni)
          acc[mi][ni] = __builtin_amdgcn_mfma_f32_16x16x32_bf16(a[mi], b[ni], acc[mi][ni], 0, 0, 0);
    }
    __builtin_amdgcn_s_setprio(0);
  };

  constexpr int NIT = kF / 64;  // 56
  STAGE(0, 0);
  STAGE(1, 64);                 // 12 loads in flight per thread
  for (int it = 0; it < NIT; ++it) {
    const int cur = it & 1;
    if (it + 1 < NIT) asm volatile("s_waitcnt vmcnt(6)" ::: "memory");
    else              asm volatile("s_waitcnt vmcnt(0)" ::: "memory");
    asm volatile("s_barrier" ::: "memory");
    MFMA_PHASE(cur);
    asm volatile("s_barrier" ::: "memory");
    if (it + 2 < NIT) STAGE(cur, (it + 2) * 64);
  }

#pragma unroll
  for (int mi = 0; mi < 4; ++mi)
#pragma unroll
    for (int i = 0; i < 4; ++i) {
      const int row = wr * 64 + mi * 16 + lq * 4 + i;
      const int pid = ppid[row];
      if (pid < 0) continue;
      const int tok = pid >> 1;
      const float w = rw[pid];
      float* op = out + (size_t)tok * kH + h0 + wc * 32 + lr;
#pragma unroll
      for (int ni = 0; ni < 2; ++ni)
        atomicAdd(&op[ni * 16], w * acc[mi][ni][i]);
    }
}

// ===========================================================================
// FALLBACK PATH (ws too small): R7 kernels, known-good 342 us.
// ===========================================================================
struct StageM { float4 a[2][2], b1[2][2], b3[2][2]; };

__global__ __launch_bounds__(256) void moe_mid_mfma(
    const float* __restrict__ x, const float* __restrict__ w1,
    const float* __restrict__ w3, const int* __restrict__ cnt,
    const int* __restrict__ list, unsigned short* __restrict__ hmid) {
  const int e = blockIdx.z;
  const int n = cnt[e];
  const int t0 = blockIdx.y * 64;
  if (t0 >= n) return;
  const int f0 = blockIdx.x * 64;

  __shared__ short As[2][64 * 64];
  __shared__ short B1s[2][64 * 64];
  __shared__ short B3s[2][64 * 64];
  __shared__ int ppid[64];
  __shared__ int ptok[64];

  const int tid = threadIdx.x;
  if (tid < 64) {
    const int idx = t0 + tid;
    const int pid = (idx < n) ? list[e * kT + idx] : -1;
    ppid[tid] = pid;
    ptok[tid] = (pid < 0) ? 0 : (pid >> 1);
  }
  __syncthreads();

  const float* w1e = w1 + (size_t)e * kF * kH;
  const float* w3e = w3 + (size_t)e * kF * kH;

  const float* a_src[2]; const float* b1_src[2]; const float* b3_src[2];
  int sw_[2];
#pragma unroll
  for (int i = 0; i < 2; ++i) {
    const int flat = tid + 256 * i;
    const int row = flat >> 3, u = flat & 7;
    a_src[i]  = x + (size_t)ptok[row] * kH + u * 8;
    b1_src[i] = w1e + (size_t)(f0 + row) * kH + u * 8;
    b3_src[i] = w3e + (size_t)(f0 + row) * kH + u * 8;
    sw_[i] = swz(row, u);
  }

  const int lane = tid & 63, wid = tid >> 6;
  const int wr = wid >> 1, wc = wid & 1;
  const int lr = lane & 15, lq = lane >> 4;

  fx4 acc1[2][2], acc3[2][2];
#pragma unroll
  for (int i = 0; i < 2; ++i)
#pragma unroll
    for (int j = 0; j < 2; ++j) { acc1[i][j] = (fx4)(0.f); acc3[i][j] = (fx4)(0.f); }

  auto LOAD = [&](StageM& S, int k0) {
#pragma unroll
    for (int i = 0; i < 2; ++i) {
      S.a[i][0]  = *reinterpret_cast<const float4*>(a_src[i] + k0);
      S.a[i][1]  = *reinterpret_cast<const float4*>(a_src[i] + k0 + 4);
      S.b1[i][0] = *reinterpret_cast<const float4*>(b1_src[i] + k0);
      S.b1[i][1] = *reinterpret_cast<const float4*>(b1_src[i] + k0 + 4);
      S.b3[i][0] = *reinterpret_cast<const float4*>(b3_src[i] + k0);
      S.b3[i][1] = *reinterpret_cast<const float4*>(b3_src[i] + k0 + 4);
    }
  };
  auto STORE = [&](const StageM& S, int buf) {
#pragma unroll
    for (int i = 0; i < 2; ++i) {
      *reinterpret_cast<bf16x8*>(&As[buf][sw_[i]])  = pack8(S.a[i][0], S.a[i][1]);
      *reinterpret_cast<bf16x8*>(&B1s[buf][sw_[i]]) = pack8(S.b1[i][0], S.b1[i][1]);
      *reinterpret_cast<bf16x8*>(&B3s[buf][sw_[i]]) = pack8(S.b3[i][0], S.b3[i][1]);
    }
  };
  auto MFMA_PHASE = [&](int buf) {
    const short* Ab = As[buf]; const short* B1b = B1s[buf]; const short* B3b = B3s[buf];
    __builtin_amdgcn_s_setprio(1);
#pragma unroll
    for (int ks = 0; ks < 2; ++ks) {
      bf16x8 a[2], bb1[2], bb3[2];
#pragma unroll
      for (int mi = 0; mi < 2; ++mi)
        a[mi] = *reinterpret_cast<const bf16x8*>(&Ab[swz(wr * 32 + mi * 16 + lr, ks * 4 + lq)]);
#pragma unroll
      for (int ni = 0; ni < 2; ++ni) {
        bb1[ni] = *reinterpret_cast<const bf16x8*>(&B1b[swz(wc * 32 + ni * 16 + lr, ks * 4 + lq)]);
        bb3[ni] = *reinterpret_cast<const bf16x8*>(&B3b[swz(wc * 32 + ni * 16 + lr, ks * 4 + lq)]);
      }
#pragma unroll
      for (int mi = 0; mi < 2; ++mi)
#pragma unroll
        for (int ni = 0; ni < 2; ++ni) {
          acc1[mi][ni] = __builtin_amdgcn_mfma_f32_16x16x32_bf16(a[mi], bb1[ni], acc1[mi][ni], 0, 0, 0);
          acc3[mi][ni] = __builtin_amdgcn_mfma_f32_16x16x32_bf16(a[mi], bb3[ni], acc3[mi][ni], 0, 0, 0);
        }
    }
    __builtin_amdgcn_s_setprio(0);
  };

  StageM R0, R1;
  constexpr int NIT = kH / 64;
  LOAD(R0, 0);
  LOAD(R1, 64);
  STORE(R0, 0);
  __syncthreads();
#pragma unroll 2
  for (int it = 0; it < NIT; ++it) {
    if (it & 1) {
      if (it + 2 < NIT) LOAD(R1, (it + 2) * 64);
      MFMA_PHASE(1);
      if (it + 1 < NIT) STORE(R0, 0);
    } else {
      if (it + 2 < NIT) LOAD(R0, (it + 2) * 64);
      MFMA_PHASE(0);
      if (it + 1 < NIT) STORE(R1, 1);
    }
    __syncthreads();
  }

#pragma unroll
  for (int mi = 0; mi < 2; ++mi)
#pragma unroll
    for (int i = 0; i < 4; ++i) {
      const int row = wr * 32 + mi * 16 + lq * 4 + i;
      const int pid = ppid[row];
      if (pid < 0) continue;
#pragma unroll
      for (int ni = 0; ni < 2; ++ni) {
        const int col = f0 + wc * 32 + ni * 16 + lr;
        const float s1 = acc1[mi][ni][i];
        const float s3 = acc3[mi][ni][i];
        const float h = s1 * s3 / (1.f + expf(-s1));
        hmid[(size_t)pid * kF + col] = (unsigned short)f2bf_s(h);
      }
    }
}

struct StageO { bf16x8 a[2]; float4 b[2][2]; };

__global__ __launch_bounds__(256) void moe_out_mfma(
    const unsigned short* __restrict__ hmid, const float* __restrict__ w2,
    const int* __restrict__ cnt, const int* __restrict__ list,
    const float* __restrict__ rw, float* __restrict__ out) {
  const int e = blockIdx.z;
  const int n = cnt[e];
  const int p0 = blockIdx.y * 64;
  if (p0 >= n) return;
  const int h0 = blockIdx.x * 64;

  __shared__ short As[2][64 * 64];
  __shared__ short Bs[2][64 * 64];
  __shared__ int ppid[64];
  __shared__ int prow[64];

  const int tid = threadIdx.x;
  if (tid < 64) {
    const int idx = p0 + tid;
    const int pid = (idx < n) ? list[e * kT + idx] : -1;
    ppid[tid] = pid;
    prow[tid] = (pid < 0) ? 0 : pid;
  }
  __syncthreads();

  const float* w2e = w2 + (size_t)e * kH * kF;

  const unsigned short* a_src[2]; const float* b_src[2];
  int sw_[2];
#pragma unroll
  for (int i = 0; i < 2; ++i) {
    const int flat = tid + 256 * i;
    const int row = flat >> 3, u = flat & 7;
    a_src[i] = hmid + (size_t)prow[row] * kF + u * 8;
    b_src[i] = w2e + (size_t)(h0 + row) * kF + u * 8;
    sw_[i] = swz(row, u);
  }

  const int lane = tid & 63, wid = tid >> 6;
  const int wr = wid >> 1, wc = wid & 1;
  const int lr = lane & 15, lq = lane >> 4;

  fx4 acc[2][2];
#pragma unroll
  for (int i = 0; i < 2; ++i)
#pragma unroll
    for (int j = 0; j < 2; ++j) acc[i][j] = (fx4)(0.f);

  auto LOAD = [&](StageO& S, int k0) {
#pragma unroll
    for (int i = 0; i < 2; ++i) {
      S.a[i]    = *reinterpret_cast<const bf16x8*>(a_src[i] + k0);
      S.b[i][0] = *reinterpret_cast<const float4*>(b_src[i] + k0);
      S.b[i][1] = *reinterpret_cast<const float4*>(b_src[i] + k0 + 4);
    }
  };
  auto STORE = [&](const StageO& S, int buf) {
#pragma unroll
    for (int i = 0; i < 2; ++i) {
      *reinterpret_cast<bf16x8*>(&As[buf][sw_[i]]) = S.a[i];
      *reinterpret_cast<bf16x8*>(&Bs[buf][sw_[i]]) = pack8(S.b[i][0], S.b[i][1]);
    }
  };
  auto MFMA_PHASE = [&](int buf) {
    const short* Ab = As[buf]; const short* Bb = Bs[buf];
    __builtin_amdgcn_s_setprio(1);
#pragma unroll
    for (int ks = 0; ks < 2; ++ks) {
      bf16x8 a[2], b[2];
#pragma unroll
      for (int mi = 0; mi < 2; ++mi)
        a[mi] = *reinterpret_cast<const bf16x8*>(&Ab[swz(wr * 32 + mi * 16 + lr, ks * 4 + lq)]);
#pragma unroll
      for (int ni = 0; ni < 2; ++ni)
        b[ni] = *reinterpret_cast<const bf16x8*>(&Bb[swz(wc * 32 + ni * 16 + lr, ks * 4 + lq)]);
#pragma unroll
      for (int mi = 0; mi < 2; ++mi)
#pragma unroll
        for (int ni = 0; ni < 2; ++ni)
          acc[mi][ni] = __builtin_amdgcn_mfma_f32_16x16x32_bf16(a[mi], b[ni], acc[mi][ni], 0, 0, 0);
    }
    __builtin_amdgcn_s_setprio(0);
  };

  StageO R0, R1;
  constexpr int NIT = kF / 64;
  LOAD(R0, 0);
  LOAD(R1, 64);
  STORE(R0, 0);
  __syncthreads();
#pragma unroll 2
  for (int it = 0; it < NIT; ++it) {
    if (it & 1) {
      if (it + 2 < NIT) LOAD(R1, (it + 2) * 64);
      MFMA_PHASE(1);
      if (it + 1 < NIT) STORE(R0, 0);
    } else {
      if (it + 2 < NIT) LOAD(R0, (it + 2) * 64);
      MFMA_PHASE(0);
      if (it + 1 < NIT) STORE(R1, 1);
    }
    __syncthreads();
  }

#pragma unroll
  for (int mi = 0; mi < 2; ++mi)
#pragma unroll
    for (int i = 0; i < 4; ++i) {
      const int row = wr * 32 + mi * 16 + lq * 4 + i;
      const int pid = ppid[row];
      if (pid < 0) continue;
      const int tok = pid >> 1;
      const float w = rw[pid];
      float* op = out + (size_t)tok * kH + h0 + wc * 32 + lr;
#pragma unroll
      for (int ni = 0; ni < 2; ++ni)
        atomicAdd(&op[ni * 16], w * acc[mi][ni][i]);
    }
}

// ---------------------------------------------------------------------------
extern "C" void kernel_launch(void* const* d_in, const int* in_sizes, int n_in,
                              void* d_out, int out_size, void* d_ws,
                              size_t ws_size, hipStream_t stream) {
  (void)in_sizes; (void)n_in; (void)out_size;
  const float* x  = (const float*)d_in[0];  // [1,2048,1024]
  const float* gw = (const float*)d_in[1];  // [8,1024]
  const float* w1 = (const float*)d_in[2];  // [8,3584,1024]
  const float* w2 = (const float*)d_in[3];  // [8,1024,3584]
  const float* w3 = (const float*)d_in[4];  // [8,3584,1024]

  float* out    = (float*)d_out;             // [2048*1024]
  float* logits = out + (size_t)kT * kH;     // [2048*8]

  char* ws = (char*)d_ws;
  int*            cnt  = (int*)(ws + OFF_CNT);
  int*            list = (int*)(ws + OFF_LIST);
  float*          rw   = (float*)(ws + OFF_RW);
  unsigned short* hmid = (unsigned short*)(ws + OFF_HMID);

  hipMemsetAsync(out, 0, (size_t)kT * kH * sizeof(float), stream);
  hipMemsetAsync(cnt, 0, kE * sizeof(int), stream);

  router_kernel<<<kT, 256, 0, stream>>>(x, gw, logits, cnt, list, rw);

  if (ws_size >= WS_NEED) {
    unsigned short* xb  = (unsigned short*)(ws + OFF_XB);
    unsigned short* w1b = (unsigned short*)(ws + OFF_W1B);
    unsigned short* w3b = (unsigned short*)(ws + OFF_W3B);
    unsigned short* w2b = (unsigned short*)(ws + OFF_W2B);

    cast_all_kernel<<<2048, 256, 0, stream>>>(x, w1, w3, w2, xb);

    dim3 g1(kF / 64, kT / 128, kE);   // (56, 16, 8)
    moe_mid_gl<<<g1, 256, 0, stream>>>(xb, w1b, w3b, cnt, list, hmid);

    dim3 g2(kH / 64, kT / 128, kE);   // (16, 16, 8)
    moe_out_gl<<<g2, 256, 0, stream>>>(hmid, w2b, cnt, list, rw, out);
  } else {
    dim3 g1(kF / 64, kT / 64, kE);   // (56, 32, 8)
    moe_mid_mfma<<<g1, 256, 0, stream>>>(x, w1, w3, cnt, list, hmid);

    dim3 g2(kH / 64, kT / 64, kE);   // (16, 32, 8)
    moe_out_mfma<<<g2, 256, 0, stream>>>(hmid, w2, cnt, list, rw, out);
  }
}